// Round 9
// baseline (18877.330 us; speedup 1.0000x reference)
//
#include <hip/hip_runtime.h>
#include <math.h>

#define BB 32
#define SS 256
#define EE 512
#define HH 1024
#define DD 2048
#define VV 10000

typedef __attribute__((ext_vector_type(8))) short short8v;   // 8 bf16 frag
typedef __attribute__((ext_vector_type(4))) float f32x4;     // C/D frag

typedef unsigned short ushort_t;
typedef unsigned long long u64;

// ---------------------------------------------------------------------------
// MFMA path (round-8 verified core): C[b][n] via mfma_f32_16x16x32_bf16.
// fp32 emulated as hi+lo bf16 (3 products) for gates/enc (recurrence-critical).
// NEW (round 9): fc uses HI-PLANE-ONLY weights (2 products) -> logit err
// ~1e-3 (far under 0.0868 store threshold); exact argmax restored by a tiny
// per-step rescue kernel: candidates within DELTA of approx max re-dotted in
// fp32 vs original fcW. fc re-tiled 209 blocks x 48 rows (82% CU util).
// Decoder hot set 84+41=125 MB -> L3-resident.
// ---------------------------------------------------------------------------

#define DELTA 0.125f

__device__ __forceinline__ ushort_t f2bf(float f) {  // RTN-even fp32->bf16
  unsigned u = __float_as_uint(f);
  return (ushort_t)((u + 0x7FFFu + ((u >> 16) & 1u)) >> 16);
}
__device__ __forceinline__ float bf2f(ushort_t h) {
  return __uint_as_float(((unsigned)h) << 16);
}
__device__ __forceinline__ float sigm(float v) { return 1.0f / (1.0f + expf(-v)); }

union Frag { short8v v; ushort_t u[8]; };

// ---------------- one-time packing kernels ---------------------------------
__global__ __launch_bounds__(256) void k_pack_wdec(const float* __restrict__ Whh,
                                                   const float* __restrict__ Wih,
                                                   ushort_t* __restrict__ Wp) {
  int i = blockIdx.x * 256 + threadIdx.x;       // (fpkt 80, nt 512, lane 64)
  int lane = i & 63, nt = (i >> 6) & 511, fpkt = i >> 15;
  int rho = nt * 16 + (lane & 15);
  int blk = rho >> 5, idx = rho & 31, g = idx >> 3, c = idx & 7;
  int n = g * DD + blk * 8 + c;
  int k0 = fpkt * 32 + (lane >> 4) * 8;
  const float* src = (k0 < DD) ? (Whh + (size_t)n * DD + k0)
                               : (Wih + (size_t)n * EE + (k0 - DD));
  size_t ohi = ((((size_t)fpkt * 2 + 0) * 512 + nt) * 64 + lane) * 8;
  size_t olo = ((((size_t)fpkt * 2 + 1) * 512 + nt) * 64 + lane) * 8;
#pragma unroll
  for (int e = 0; e < 8; ++e) {
    float v = src[e];
    ushort_t hi = f2bf(v);
    Wp[ohi + e] = hi;
    Wp[olo + e] = f2bf(v - bf2f(hi));
  }
}

// fc: HI plane only, 627 ntiles (10032 rows, padded)
__global__ __launch_bounds__(256) void k_pack_wfc(const float* __restrict__ fcW,
                                                  ushort_t* __restrict__ Wp) {
  int i = blockIdx.x * 256 + threadIdx.x;       // 64 kt x 627 nt x 64 lane
  int lane = i & 63;
  int rest = i >> 6;
  int nt = rest % 627;
  int kt = rest / 627;
  int rho = nt * 16 + (lane & 15);
  int n = rho < VV ? rho : VV - 1;
  int k0 = kt * 32 + (lane >> 4) * 8;
  const float* src = fcW + (size_t)n * DD + k0;
  size_t o = (((size_t)kt * 627 + nt) * 64 + lane) * 8;
#pragma unroll
  for (int e = 0; e < 8; ++e) Wp[o + e] = f2bf(src[e]);
}

__global__ __launch_bounds__(256) void k_pack_wenc(
    const float* __restrict__ Whh_f, const float* __restrict__ Wih_f,
    const float* __restrict__ Whh_b, const float* __restrict__ Wih_b,
    ushort_t* __restrict__ Wp) {
  int i = blockIdx.x * 256 + threadIdx.x;       // (fpkt 48, nt 512, lane 64)
  int lane = i & 63, nt = (i >> 6) & 511, fpkt = i >> 15;
  int rho = nt * 16 + (lane & 15);
  int blk = rho >> 5, idx = rho & 31, g = idx >> 3, c = idx & 7;
  int dir = blk >> 7;
  int r = g * HH + (blk & 127) * 8 + c;
  const float* Whh = dir ? Whh_b : Whh_f;
  const float* Wih = dir ? Wih_b : Wih_f;
  int k0 = fpkt * 32 + (lane >> 4) * 8;
  const float* src = (k0 < HH) ? (Whh + (size_t)r * HH + k0)
                               : (Wih + (size_t)r * EE + (k0 - HH));
  size_t ohi = ((((size_t)fpkt * 2 + 0) * 512 + nt) * 64 + lane) * 8;
  size_t olo = ((((size_t)fpkt * 2 + 1) * 512 + nt) * 64 + lane) * 8;
#pragma unroll
  for (int e = 0; e < 8; ++e) {
    float v = src[e];
    ushort_t hi = f2bf(v);
    Wp[ohi + e] = hi;
    Wp[olo + e] = f2bf(v - bf2f(hi));
  }
}

__global__ __launch_bounds__(256) void k_zero32(unsigned* __restrict__ p, int n) {
  int i = blockIdx.x * 256 + threadIdx.x;
  if (i < n) p[i] = 0u;
}
__global__ __launch_bounds__(256) void k_out0(float* __restrict__ out) {
  int i = blockIdx.x * 256 + threadIdx.x;
  if (i < BB * VV) out[(size_t)(i / VV) * SS * VV + (i % VV)] = 0.0f;
}

// write one fp32 value as hi/lo planes into act-frag array
__device__ __forceinline__ void pack_act(ushort_t* __restrict__ dst, int j, int b,
                                         float v) {
  int fpkt = j >> 5, kloc = j & 31;
  int lane = (kloc >> 3) * 16 + (b & 15);
  int e = kloc & 7, mt = b >> 4;
  ushort_t hi = f2bf(v);
  dst[((((size_t)fpkt * 2 + 0) * 2 + mt) * 64 + lane) * 8 + e] = hi;
  dst[((((size_t)fpkt * 2 + 1) * 2 + mt) * 64 + lane) * 8 + e] = f2bf(v - bf2f(hi));
}

__device__ __forceinline__ void split8(const float* __restrict__ src, Frag& fh,
                                       Frag& fl) {
  float4 v0 = *(const float4*)src;
  float4 v1 = *(const float4*)(src + 4);
  float vv[8] = {v0.x, v0.y, v0.z, v0.w, v1.x, v1.y, v1.z, v1.w};
#pragma unroll
  for (int e = 0; e < 8; ++e) {
    ushort_t hi = f2bf(vv[e]);
    fh.u[e] = hi;
    fl.u[e] = f2bf(vv[e] - bf2f(hi));
  }
}

// ---------------- encoder step (both dirs), MFMA -----------------------------
__global__ __launch_bounds__(512) void k_enc_mfma(
    int t, const int* __restrict__ x, const float* __restrict__ emb,
    const ushort_t* __restrict__ Wp, ushort_t* __restrict__ hencp,
    float* __restrict__ cT2, float* __restrict__ hT2,
    const float* __restrict__ b_f, const float* __restrict__ b_b) {
  __shared__ float red[8 * 2 * 2 * 64 * 4];
  __shared__ int stoks[32];
  const int tid = threadIdx.x, w = tid >> 6, lane = tid & 63;
  const int dir = blockIdx.x >> 7, jb = (blockIdx.x & 127) * 8;
  const int s = dir ? (SS - 1 - t) : t;
  const int pin = t & 1;
  const size_t HEP = 32 * 2 * 2 * 64 * 8;
  const ushort_t* hin = hencp + (dir * 2 + pin) * HEP;
  ushort_t* hout = hencp + (dir * 2 + (pin ^ 1)) * HEP;
  if (tid < 32) stoks[tid] = x[tid * SS + s];
  __syncthreads();

  f32x4 acc[2][2];
#pragma unroll
  for (int a = 0; a < 2; ++a)
#pragma unroll
    for (int bq = 0; bq < 2; ++bq) acc[a][bq] = (f32x4){0.f, 0.f, 0.f, 0.f};

  for (int i = 0; i < 6; ++i) {
    const int kt = w + 8 * i;
    Frag ah[2], al[2], wh[2], wl[2];
    if (kt < 32) {
#pragma unroll
      for (int mt = 0; mt < 2; ++mt) {
        ah[mt].v = *(const short8v*)(hin + ((((size_t)kt * 2 + 0) * 2 + mt) * 64 + lane) * 8);
        al[mt].v = *(const short8v*)(hin + ((((size_t)kt * 2 + 1) * 2 + mt) * 64 + lane) * 8);
      }
    } else {
      const int ke = (kt - 32) * 32 + (lane >> 4) * 8;
#pragma unroll
      for (int mt = 0; mt < 2; ++mt) {
        const int b = mt * 16 + (lane & 15);
        split8(emb + (size_t)stoks[b] * EE + ke, ah[mt], al[mt]);
      }
    }
#pragma unroll
    for (int nt = 0; nt < 2; ++nt) {
      const size_t ntg = blockIdx.x * 2 + nt;
      wh[nt].v = *(const short8v*)(Wp + ((((size_t)kt * 2 + 0) * 512 + ntg) * 64 + lane) * 8);
      wl[nt].v = *(const short8v*)(Wp + ((((size_t)kt * 2 + 1) * 512 + ntg) * 64 + lane) * 8);
    }
#pragma unroll
    for (int mt = 0; mt < 2; ++mt)
#pragma unroll
      for (int nt = 0; nt < 2; ++nt) {
        acc[mt][nt] = __builtin_amdgcn_mfma_f32_16x16x32_bf16(ah[mt].v, wh[nt].v, acc[mt][nt], 0, 0, 0);
        acc[mt][nt] = __builtin_amdgcn_mfma_f32_16x16x32_bf16(ah[mt].v, wl[nt].v, acc[mt][nt], 0, 0, 0);
        acc[mt][nt] = __builtin_amdgcn_mfma_f32_16x16x32_bf16(al[mt].v, wh[nt].v, acc[mt][nt], 0, 0, 0);
      }
  }
#pragma unroll
  for (int mt = 0; mt < 2; ++mt)
#pragma unroll
    for (int nt = 0; nt < 2; ++nt)
      ((f32x4*)red)[((w * 2 + mt) * 2 + nt) * 64 + lane] = acc[mt][nt];
  __syncthreads();

  if (tid < 256) {
    const int c = tid >> 5, b = tid & 31;
    const float* bias = dir ? b_b : b_f;
    const int mt = b >> 4, lg = (b & 15) >> 2, reg = b & 3;
    float g4[4];
#pragma unroll
    for (int g = 0; g < 4; ++g) {
      const int rho = g * 8 + c;
      const int nt = rho >> 4, l15 = rho & 15;
      float v = bias[g * HH + jb + c];
#pragma unroll
      for (int w2 = 0; w2 < 8; ++w2)
        v += red[(((w2 * 2 + mt) * 2 + nt) * 64 + lg * 16 + l15) * 4 + reg];
      g4[g] = v;
    }
    const int j = jb + c;
    float* cT = cT2 + dir * (HH * BB);
    float* hT = hT2 + dir * (HH * BB);
    const int idx = j * BB + b;
    float cv = fmaf(sigm(g4[1]), cT[idx], sigm(g4[0]) * tanhf(g4[2]));
    cT[idx] = cv;
    float h = sigm(g4[3]) * tanhf(cv);
    hT[idx] = h;
    pack_act(hout, j, b, h);
  }
}

// BN + relu on concat(hf,hb) -> packed hd'[parity 0]
__global__ __launch_bounds__(256) void k_bn_handoff(
    const float* __restrict__ hT2, const float* __restrict__ gamma,
    const float* __restrict__ beta, ushort_t* __restrict__ hdp) {
  const int d = blockIdx.x * 8 + (threadIdx.x >> 5);
  const int b = threadIdx.x & 31;
  float v = hT2[(d < HH ? d * BB : (HH * BB) + (d - HH) * BB) + b];
  float sum = v;
  for (int m = 16; m >= 1; m >>= 1) sum += __shfl_xor(sum, m, 32);
  float mean = sum * (1.0f / BB);
  float dx = v - mean;
  float s2 = dx * dx;
  for (int m = 16; m >= 1; m >>= 1) s2 += __shfl_xor(s2, m, 32);
  float var = s2 * (1.0f / BB);
  float y = fmaxf(dx * (1.0f / sqrtf(var + 1e-5f)) * gamma[d] + beta[d], 0.0f);
  pack_act(hdp, d, b, y);
}

// ---------------- decoder gates, MFMA ----------------------------------------
__global__ __launch_bounds__(512) void k_dec_mfma(
    int t, const int* __restrict__ x, const float* __restrict__ emb,
    const ushort_t* __restrict__ Wp, ushort_t* __restrict__ hdp,
    float* __restrict__ cdT, ushort_t* __restrict__ outp,
    float* __restrict__ outF,
    const float* __restrict__ bias, const float* __restrict__ gamma,
    const float* __restrict__ beta, const int* __restrict__ tokens) {
  __shared__ float red[8 * 2 * 2 * 64 * 4];
  __shared__ int stoks[32];
  const int tid = threadIdx.x, w = tid >> 6, lane = tid & 63;
  const int jb = blockIdx.x * 8;
  const int pin = t & 1;
  const size_t HDP = 64 * 2 * 2 * 64 * 8;
  const ushort_t* hin = hdp + pin * HDP;
  ushort_t* hout = hdp + (pin ^ 1) * HDP;
  if (tid < 32) stoks[tid] = (t == 0) ? x[tid * SS] : tokens[tid];
  __syncthreads();

  f32x4 acc[2][2];
#pragma unroll
  for (int a = 0; a < 2; ++a)
#pragma unroll
    for (int bq = 0; bq < 2; ++bq) acc[a][bq] = (f32x4){0.f, 0.f, 0.f, 0.f};

  for (int i = 0; i < 10; ++i) {
    const int kt = w + 8 * i;
    Frag ah[2], al[2], wh[2], wl[2];
    if (kt < 64) {
#pragma unroll
      for (int mt = 0; mt < 2; ++mt) {
        ah[mt].v = *(const short8v*)(hin + ((((size_t)kt * 2 + 0) * 2 + mt) * 64 + lane) * 8);
        al[mt].v = *(const short8v*)(hin + ((((size_t)kt * 2 + 1) * 2 + mt) * 64 + lane) * 8);
      }
    } else {
      const int ke = (kt - 64) * 32 + (lane >> 4) * 8;
#pragma unroll
      for (int mt = 0; mt < 2; ++mt) {
        const int b = mt * 16 + (lane & 15);
        split8(emb + (size_t)stoks[b] * EE + ke, ah[mt], al[mt]);
      }
    }
#pragma unroll
    for (int nt = 0; nt < 2; ++nt) {
      const size_t ntg = blockIdx.x * 2 + nt;
      wh[nt].v = *(const short8v*)(Wp + ((((size_t)kt * 2 + 0) * 512 + ntg) * 64 + lane) * 8);
      wl[nt].v = *(const short8v*)(Wp + ((((size_t)kt * 2 + 1) * 512 + ntg) * 64 + lane) * 8);
    }
#pragma unroll
    for (int mt = 0; mt < 2; ++mt)
#pragma unroll
      for (int nt = 0; nt < 2; ++nt) {
        acc[mt][nt] = __builtin_amdgcn_mfma_f32_16x16x32_bf16(ah[mt].v, wh[nt].v, acc[mt][nt], 0, 0, 0);
        acc[mt][nt] = __builtin_amdgcn_mfma_f32_16x16x32_bf16(ah[mt].v, wl[nt].v, acc[mt][nt], 0, 0, 0);
        acc[mt][nt] = __builtin_amdgcn_mfma_f32_16x16x32_bf16(al[mt].v, wh[nt].v, acc[mt][nt], 0, 0, 0);
      }
  }
#pragma unroll
  for (int mt = 0; mt < 2; ++mt)
#pragma unroll
    for (int nt = 0; nt < 2; ++nt)
      ((f32x4*)red)[((w * 2 + mt) * 2 + nt) * 64 + lane] = acc[mt][nt];
  __syncthreads();

  if (tid < 256) {
    const int c = tid >> 5, b = tid & 31;
    const int mt = b >> 4, lg = (b & 15) >> 2, reg = b & 3;
    float g4[4];
#pragma unroll
    for (int g = 0; g < 4; ++g) {
      const int rho = g * 8 + c;
      const int nt = rho >> 4, l15 = rho & 15;
      float v = bias[g * DD + jb + c];
#pragma unroll
      for (int w2 = 0; w2 < 8; ++w2)
        v += red[(((w2 * 2 + mt) * 2 + nt) * 64 + lg * 16 + l15) * 4 + reg];
      g4[g] = v;
    }
    const int j = jb + c;
    const int idx = j * BB + b;
    float cv = fmaf(sigm(g4[1]), cdT[idx], sigm(g4[0]) * tanhf(g4[2]));
    cdT[idx] = cv;
    float h = sigm(g4[3]) * tanhf(cv);
    pack_act(hout, j, b, h);
    // fused BN over batch + relu -> packed fc input + fp32 copy for rescue
    float sum = h;
    for (int m = 16; m >= 1; m >>= 1) sum += __shfl_xor(sum, m, 32);
    float mean = sum * (1.0f / BB);
    float dx = h - mean;
    float s2v = dx * dx;
    for (int m = 16; m >= 1; m >>= 1) s2v += __shfl_xor(s2v, m, 32);
    float var = s2v * (1.0f / BB);
    float y = fmaxf(dx * (1.0f / sqrtf(var + 1e-5f)) * gamma[j] + beta[j], 0.0f);
    pack_act(outp, j, b, y);
    outF[(size_t)b * DD + j] = y;
  }
}

// ---------------- fc approx (hi-plane weights), 209 blocks x 48 rows ---------
__global__ __launch_bounds__(512) void k_fc_approx(
    int t, const ushort_t* __restrict__ outp, const ushort_t* __restrict__ Wp,
    const float* __restrict__ fcb, float* __restrict__ out) {
  __shared__ float red[8 * 2 * 3 * 64 * 4];   // 48 KB
  const int tid = threadIdx.x, w = tid >> 6, lane = tid & 63;

  f32x4 acc[2][3];
#pragma unroll
  for (int a = 0; a < 2; ++a)
#pragma unroll
    for (int bq = 0; bq < 3; ++bq) acc[a][bq] = (f32x4){0.f, 0.f, 0.f, 0.f};

  for (int i = 0; i < 8; ++i) {
    const int kt = w + 8 * i;
    Frag ah[2], al[2], wh[3];
#pragma unroll
    for (int mt = 0; mt < 2; ++mt) {
      ah[mt].v = *(const short8v*)(outp + ((((size_t)kt * 2 + 0) * 2 + mt) * 64 + lane) * 8);
      al[mt].v = *(const short8v*)(outp + ((((size_t)kt * 2 + 1) * 2 + mt) * 64 + lane) * 8);
    }
#pragma unroll
    for (int nt = 0; nt < 3; ++nt) {
      const size_t ntg = blockIdx.x * 3 + nt;
      wh[nt].v = *(const short8v*)(Wp + (((size_t)kt * 627 + ntg) * 64 + lane) * 8);
    }
#pragma unroll
    for (int mt = 0; mt < 2; ++mt)
#pragma unroll
      for (int nt = 0; nt < 3; ++nt) {
        acc[mt][nt] = __builtin_amdgcn_mfma_f32_16x16x32_bf16(ah[mt].v, wh[nt].v, acc[mt][nt], 0, 0, 0);
        acc[mt][nt] = __builtin_amdgcn_mfma_f32_16x16x32_bf16(al[mt].v, wh[nt].v, acc[mt][nt], 0, 0, 0);
      }
  }
#pragma unroll
  for (int mt = 0; mt < 2; ++mt)
#pragma unroll
    for (int nt = 0; nt < 3; ++nt)
      ((f32x4*)red)[((w * 2 + mt) * 3 + nt) * 64 + lane] = acc[mt][nt];
  __syncthreads();

  {
    const int r2 = tid >> 5, b = tid & 31;   // r2 0..15
    const int mt = b >> 4, lg = (b & 15) >> 2, reg = b & 3;
    const size_t obase = (size_t)b * SS * VV + (size_t)(t + 1) * VV;
#pragma unroll
    for (int q = 0; q < 3; ++q) {
      const int lrow = q * 16 + r2;               // nt = q, l15 = r2
      const int v = blockIdx.x * 48 + lrow;
      if (v < VV) {
        float val = fcb[v];
#pragma unroll
        for (int w2 = 0; w2 < 8; ++w2)
          val += red[(((w2 * 2 + mt) * 3 + q) * 64 + lg * 16 + r2) * 4 + reg];
        out[obase + v] = val;
      }
    }
  }
}

// ---------------- rescue: exact argmax from approx logits --------------------
// 32 blocks (one per batch), 256 threads.
__global__ __launch_bounds__(256) void k_rescue(
    int t, const float* __restrict__ out, const float* __restrict__ fcW,
    const float* __restrict__ fcb, const float* __restrict__ outF,
    int* __restrict__ tokens) {
  __shared__ float samax[4];
  __shared__ int cnt;
  __shared__ int cand[64];
  __shared__ float exactv[64];
  const int b = blockIdx.x;
  const int tid = threadIdx.x, lane = tid & 63, w = tid >> 6;
  const float* __restrict__ row = out + (size_t)b * SS * VV + (size_t)(t + 1) * VV;

  float mv = -INFINITY;
  for (int v = tid; v < VV; v += 256) mv = fmaxf(mv, row[v]);
#pragma unroll
  for (int m = 32; m >= 1; m >>= 1) mv = fmaxf(mv, __shfl_xor(mv, m));
  if (lane == 0) samax[w] = mv;
  if (tid == 0) cnt = 0;
  __syncthreads();
  const float amax = fmaxf(fmaxf(samax[0], samax[1]), fmaxf(samax[2], samax[3]));
  const float thr = amax - DELTA;
  for (int v = tid; v < VV; v += 256) {
    if (row[v] >= thr) {
      int idx = atomicAdd(&cnt, 1);
      if (idx < 64) cand[idx] = v;
    }
  }
  __syncthreads();
  const int nc = min(cnt, 64);
  for (int ci = w; ci < nc; ci += 4) {
    const int v = cand[ci];
    const float* __restrict__ wr = fcW + (size_t)v * DD;
    const float* __restrict__ av = outF + (size_t)b * DD;
    float sum = 0.f;
    for (int k = lane; k < DD; k += 64) sum = fmaf(wr[k], av[k], sum);
#pragma unroll
    for (int m = 32; m >= 1; m >>= 1) sum += __shfl_xor(sum, m);
    if (lane == 0) exactv[ci] = sum + fcb[v];
  }
  __syncthreads();
  if (tid == 0) {
    float bv = -INFINITY;
    int bi = 0x7fffffff;
    for (int ci = 0; ci < nc; ++ci) {
      float e = exactv[ci];
      int v = cand[ci];
      if (e > bv || (e == bv && v < bi)) { bv = e; bi = v; }
    }
    tokens[b] = bi;
  }
}

// ============================ launch =========================================
extern "C" void kernel_launch(void* const* d_in, const int* in_sizes, int n_in,
                              void* d_out, int out_size, void* d_ws, size_t ws_size,
                              hipStream_t stream) {
  const int*   x         = (const int*)d_in[0];
  const float* emb       = (const float*)d_in[1];
  const float* Wih_f     = (const float*)d_in[2];
  const float* Whh_f     = (const float*)d_in[3];
  const float* b_f       = (const float*)d_in[4];
  const float* Wih_b     = (const float*)d_in[5];
  const float* Whh_b     = (const float*)d_in[6];
  const float* b_b       = (const float*)d_in[7];
  const float* Wih_d     = (const float*)d_in[8];
  const float* Whh_d     = (const float*)d_in[9];
  const float* b_d       = (const float*)d_in[10];
  const float* enc_gamma = (const float*)d_in[11];
  const float* enc_beta  = (const float*)d_in[12];
  const float* dec_gamma = (const float*)d_in[13];
  const float* dec_beta  = (const float*)d_in[14];
  const float* fcW       = (const float*)d_in[15];
  const float* fcb       = (const float*)d_in[16];
  float* out = (float*)d_out;

  // ---- ws layout (ushort regions first, 16B-aligned) ----
  const size_t WDEC_U = (size_t)80 * 2 * 512 * 512;   // 41,943,040
  const size_t WFC_U  = (size_t)64 * 627 * 512;       // 20,545,536 (hi only)
  const size_t WENC_U = (size_t)48 * 2 * 512 * 512;   // 25,165,824
  const size_t HDP_U  = (size_t)64 * 2 * 2 * 512;     // 131,072 per parity
  const size_t HEP_U  = (size_t)32 * 2 * 2 * 512;     // 65,536 per buffer

  ushort_t* us = (ushort_t*)d_ws;
  ushort_t* Wpdec = us;               us += WDEC_U;
  ushort_t* Wpfc  = us;               us += WFC_U;
  ushort_t* Wpenc = us;               us += WENC_U;
  ushort_t* hdp   = us;               us += 2 * HDP_U;   // decoder h ping-pong
  ushort_t* outp  = us;               us += HDP_U;       // fc input (packed)
  ushort_t* hencp = us;               us += 4 * HEP_U;   // enc h [dir][pp]
  float* f = (float*)us;
  float* cT2  = f;  f += HH * BB * 2;                    // cfT | cbT
  float* cdT  = f;  f += DD * BB;
  float* hT2  = f;  f += HH * BB * 2;                    // hfT | hbT (fp32)
  float* outF = f;  f += DD * BB;                        // fp32 BN output [b][d]
  int* tokens = (int*)f;

  // one-time packs
  k_pack_wdec<<<10240, 256, 0, stream>>>(Whh_d, Wih_d, Wpdec);
  k_pack_wfc<<<10032, 256, 0, stream>>>(fcW, Wpfc);
  k_pack_wenc<<<6144, 256, 0, stream>>>(Whh_f, Wih_f, Whh_b, Wih_b, Wpenc);

  // zero packed-act buffers + fp32 states + tokens (contiguous from hdp)
  {
    size_t zbytes = (2 * HDP_U + HDP_U + 4 * HEP_U) * 2 +
                    (size_t)(HH * BB * 2 + DD * BB + HH * BB * 2 + DD * BB) * 4 +
                    128;
    int zn = (int)(zbytes / 4);
    k_zero32<<<(zn + 255) / 256, 256, 0, stream>>>((unsigned*)hdp, zn);
  }
  k_out0<<<(BB * VV + 255) / 256, 256, 0, stream>>>(out);

  for (int t = 0; t < SS; ++t)
    k_enc_mfma<<<256, 512, 0, stream>>>(t, x, emb, Wpenc, hencp, cT2, hT2, b_f, b_b);

  k_bn_handoff<<<DD / 8, 256, 0, stream>>>(hT2, enc_gamma, enc_beta, hdp);

  for (int t = 0; t < SS - 1; ++t) {
    k_dec_mfma<<<256, 512, 0, stream>>>(t, x, emb, Wpdec, hdp, cdT, outp, outF,
                                        b_d, dec_gamma, dec_beta, tokens);
    k_fc_approx<<<209, 512, 0, stream>>>(t, outp, Wpfc, fcb, out);
    k_rescue<<<BB, 256, 0, stream>>>(t, out, fcW, fcb, outF, tokens);
  }
}